// Round 12
// baseline (525.941 us; speedup 1.0000x reference)
//
#include <hip/hip_runtime.h>
#include <hip/hip_bf16.h>
#include <hip/hip_cooperative_groups.h>

namespace cg = cooperative_groups;

#define DIM 128
#define EPB 4096      // edges per chunk in radix phases
#define BINS 512
#define CBLK 512      // cooperative grid blocks
#define CTHR 512      // threads per cooperative block

typedef unsigned short u16;
typedef unsigned int u32;
typedef __attribute__((ext_vector_type(8))) short v8s;
typedef __attribute__((ext_vector_type(4))) float v4f;

__device__ __forceinline__ float bf2f(u16 u) {
    union { unsigned int i; float f; } v;
    v.i = ((unsigned int)u) << 16;
    return v.f;
}

__device__ __forceinline__ u16 f2bf(float f) {
    union { float f; unsigned int i; } v;
    v.f = f;
    unsigned int x = v.i;
    return (u16)((x + 0x7fffu + ((x >> 16) & 1u)) >> 16);
}

__device__ __forceinline__ uint4 pack8(float4 x0, float4 x1) {
    uint4 o;
    o.x = (u32)f2bf(x0.x) | ((u32)f2bf(x0.y) << 16);
    o.y = (u32)f2bf(x0.z) | ((u32)f2bf(x0.w) << 16);
    o.z = (u32)f2bf(x1.x) | ((u32)f2bf(x1.y) << 16);
    o.w = (u32)f2bf(x1.z) | ((u32)f2bf(x1.w) << 16);
    return o;
}

struct CvtArgs { const float* s[8]; u32 pfx[9]; };

// =============== cooperative CSR build: cvt||count -> scan -> scatter -> sort
// One launch replaces 4. 512 blocks x 512 threads, 6.6 KB LDS, grid.sync()
// between phases. Phase work identical to the proven split kernels (r10/r11).
__global__ __launch_bounds__(CTHR) void csr_coop(
    CvtArgs a, u16* __restrict__ cdst, int n8,
    const int* __restrict__ tile_src, const int* __restrict__ piece_dst,
    const int* __restrict__ piece_src, const int* __restrict__ tile_dst,
    const int* __restrict__ t_src, const int* __restrict__ t_dst,
    int EPT, int ETT, int NP, int NT,
    int* __restrict__ counts, int* __restrict__ countsS,
    int* __restrict__ bsum, int NBLK, int n2, int SB,
    int* __restrict__ T, int* __restrict__ el, int* __restrict__ rowptr)
{
    cg::grid_group grid = cg::this_grid();
    __shared__ int sh[BINS];
    __shared__ int sh2[BINS];
    __shared__ int sh3[BINS];
    __shared__ int offp[128];
    const int t = threadIdx.x;
    const int b = blockIdx.x;
    const int ET = 2 * EPT + ETT;

    // ---- P0: per-chunk histogram (blocks < NBLK) + cvt grid-stride (all) ----
    if (b < NBLK) {
        sh[t & (BINS - 1)] = 0;   // t < 512 == BINS
        __syncthreads();
        #pragma unroll
        for (int j = 0; j < EPB / CTHR; ++j) {
            int e = b * EPB + j * CTHR + t;
            if (e < ET) {
                int d;
                if (e < EPT)            d = (piece_dst[e] >> 9);
                else if (e < 2 * EPT)   d = 128 | (tile_dst[e - EPT] >> 9);
                else                    d = 256 | (t_dst[e - 2 * EPT] >> 9);
                atomicAdd(&sh[d], 1);
            }
        }
        __syncthreads();
        counts[t * NBLK + b] = sh[t];
    }
    for (int g = b * CTHR + t; g < n8; g += CBLK * CTHR) {
        u32 flat = (u32)g * 8;
        int seg = 0;
        #pragma unroll
        for (int i = 1; i < 8; ++i) if (flat >= a.pfx[i]) seg = i;
        const float4* fp = (const float4*)(a.s[seg] + (flat - a.pfx[seg]));
        *(uint4*)(cdst + flat) = pack8(fp[0], fp[1]);
    }
    grid.sync();

    // ---- P1: partial exclusive scan over counts (blocks < SB) ----
    if (b < SB) {
        const int base = b * 2048;
        int v[4]; int s = 0;
        #pragma unroll
        for (int i = 0; i < 4; ++i) {
            int idx = base + t * 4 + i;
            v[i] = (idx < n2) ? counts[idx] : 0;
            s += v[i];
        }
        sh[t] = s;
        __syncthreads();
        for (int o = 1; o < CTHR; o <<= 1) {
            int x = (t >= o) ? sh[t - o] : 0;
            __syncthreads();
            sh[t] += x;
            __syncthreads();
        }
        int run = (t == 0) ? 0 : sh[t - 1];
        #pragma unroll
        for (int i = 0; i < 4; ++i) {
            int idx = base + t * 4 + i;
            if (idx < n2) countsS[idx] = run;
            run += v[i];
        }
        if (t == CTHR - 1) bsum[b] = sh[CTHR - 1];
    }
    grid.sync();

    // ---- P2: scatter into dst>>9 buckets (blocks < NBLK) ----
    if (b < NBLK) {
        if (t < SB) offp[t] = bsum[t];
        __syncthreads();
        if (t == 0) {
            int run = 0;
            for (int i = 0; i < SB; ++i) { int v = offp[i]; offp[i] = run; run += v; }
        }
        __syncthreads();
        {
            int idx = t * NBLK + b;
            sh[t] = countsS[idx] + offp[idx >> 11];
        }
        __syncthreads();
        #pragma unroll
        for (int j = 0; j < EPB / CTHR; ++j) {
            int e = b * EPB + j * CTHR + t;
            if (e < ET) {
                int dst, src, d;
                if (e < EPT) {
                    dst = piece_dst[e]; src = tile_src[e]; d = dst >> 9;
                } else if (e < 2 * EPT) {
                    int le = e - EPT;
                    dst = tile_dst[le]; src = piece_src[le]; d = 128 | (dst >> 9);
                } else {
                    int le = e - 2 * EPT;
                    dst = t_dst[le]; src = t_src[le]; d = 256 | (dst >> 9);
                }
                int pos = atomicAdd(&sh[d], 1);
                T[pos] = ((dst & 511) << 17) | src;
            }
        }
    }
    grid.sync();

    // ---- P3: per-bucket counting sort + rowptr (all 512 blocks) ----
    {
        const int d = b;
        const int seg = d >> 7;
        const int dhi = d & 127;
        int Nseg, segOff, rb, Eseg;
        if (seg == 0)      { Nseg = NP; segOff = 0;       rb = 0;                 Eseg = EPT; }
        else if (seg == 1) { Nseg = NT; segOff = EPT;     rb = NP + 1;            Eseg = EPT; }
        else               { Nseg = NT; segOff = 2 * EPT; rb = NP + 1 + NT + 1;   Eseg = ETT; }

        if (t < SB) offp[t] = bsum[t];
        __syncthreads();
        if (t == 0) {
            int run = 0;
            for (int i = 0; i < SB; ++i) { int v = offp[i]; offp[i] = run; run += v; }
        }
        __syncthreads();
        int i0 = d * NBLK;
        const int bstart = countsS[i0] + offp[i0 >> 11];
        int bend;
        if (d < BINS - 1) { int i1 = (d + 1) * NBLK; bend = countsS[i1] + offp[i1 >> 11]; }
        else bend = ET;

        sh[t] = 0;   // hist
        __syncthreads();
        for (int j = bstart + t; j < bend; j += CTHR)
            atomicAdd(&sh[T[j] >> 17], 1);
        __syncthreads();
        int c0 = sh[t];
        sh3[t] = c0;
        __syncthreads();
        #pragma unroll
        for (int o = 1; o < BINS; o <<= 1) {
            int x = (t >= o) ? sh3[t - o] : 0;
            __syncthreads();
            sh3[t] += x;
            __syncthreads();
        }
        int ex = (t == 0) ? 0 : sh3[t - 1];
        sh2[t] = bstart + ex;   // pos
        __syncthreads();
        {
            int n = dhi * 512 + t;
            if (n < Nseg) rowptr[rb + n] = sh2[t] - segOff;
        }
        if (t == 0 && dhi == ((Nseg - 1) >> 9)) rowptr[rb + Nseg] = Eseg;
        __syncthreads();
        for (int j = bstart + t; j < bend; j += CTHR) {
            int v = T[j];
            int p = atomicAdd(&sh2[v >> 17], 1);
            el[p] = v & 0x1ffff;
        }
    }
}

// ---------------- gather-side mean: 16 lanes/row, dwordx4, 8-wide ILP -------
#define GACC(vv, p0, p1, p2, p3, p4, p5, p6, p7) do { \
    p0 += bf2f((u16)((vv).x & 0xffffu)); p1 += bf2f((u16)((vv).x >> 16)); \
    p2 += bf2f((u16)((vv).y & 0xffffu)); p3 += bf2f((u16)((vv).y >> 16)); \
    p4 += bf2f((u16)((vv).z & 0xffffu)); p5 += bf2f((u16)((vv).z >> 16)); \
    p6 += bf2f((u16)((vv).w & 0xffffu)); p7 += bf2f((u16)((vv).w >> 16)); } while (0)

__global__ __launch_bounds__(256) void gather_mean_kernel(
    const u16* __restrict__ feat,
    const int* __restrict__ elist, const int* __restrict__ rowptr,
    int N, u16* __restrict__ meanA)
{
    int node = blockIdx.x * 16 + (threadIdx.x >> 4);
    int lane = threadIdx.x & 15;
    if (node >= N) return;
    int r0 = rowptr[node], r1 = rowptr[node + 1];
    float a0 = 0.f, a1 = 0.f, a2 = 0.f, a3 = 0.f;
    float a4 = 0.f, a5 = 0.f, a6 = 0.f, a7 = 0.f;
    float b0 = 0.f, b1 = 0.f, b2 = 0.f, b3 = 0.f;
    float b4 = 0.f, b5 = 0.f, b6 = 0.f, b7 = 0.f;
    int j = r0;
    for (; j + 8 <= r1; j += 8) {
        int s0 = elist[j],     s1 = elist[j + 1], s2 = elist[j + 2], s3 = elist[j + 3];
        int s4 = elist[j + 4], s5 = elist[j + 5], s6 = elist[j + 6], s7 = elist[j + 7];
        uint4 v0 = ((const uint4*)(feat + (size_t)s0 * DIM))[lane];
        uint4 v1 = ((const uint4*)(feat + (size_t)s1 * DIM))[lane];
        uint4 v2 = ((const uint4*)(feat + (size_t)s2 * DIM))[lane];
        uint4 v3 = ((const uint4*)(feat + (size_t)s3 * DIM))[lane];
        uint4 v4 = ((const uint4*)(feat + (size_t)s4 * DIM))[lane];
        uint4 v5 = ((const uint4*)(feat + (size_t)s5 * DIM))[lane];
        uint4 v6 = ((const uint4*)(feat + (size_t)s6 * DIM))[lane];
        uint4 v7 = ((const uint4*)(feat + (size_t)s7 * DIM))[lane];
        GACC(v0, a0, a1, a2, a3, a4, a5, a6, a7);
        GACC(v1, b0, b1, b2, b3, b4, b5, b6, b7);
        GACC(v2, a0, a1, a2, a3, a4, a5, a6, a7);
        GACC(v3, b0, b1, b2, b3, b4, b5, b6, b7);
        GACC(v4, a0, a1, a2, a3, a4, a5, a6, a7);
        GACC(v5, b0, b1, b2, b3, b4, b5, b6, b7);
        GACC(v6, a0, a1, a2, a3, a4, a5, a6, a7);
        GACC(v7, b0, b1, b2, b3, b4, b5, b6, b7);
    }
    for (; j + 4 <= r1; j += 4) {
        int s0 = elist[j], s1 = elist[j + 1], s2 = elist[j + 2], s3 = elist[j + 3];
        uint4 v0 = ((const uint4*)(feat + (size_t)s0 * DIM))[lane];
        uint4 v1 = ((const uint4*)(feat + (size_t)s1 * DIM))[lane];
        uint4 v2 = ((const uint4*)(feat + (size_t)s2 * DIM))[lane];
        uint4 v3 = ((const uint4*)(feat + (size_t)s3 * DIM))[lane];
        GACC(v0, a0, a1, a2, a3, a4, a5, a6, a7);
        GACC(v1, b0, b1, b2, b3, b4, b5, b6, b7);
        GACC(v2, a0, a1, a2, a3, a4, a5, a6, a7);
        GACC(v3, b0, b1, b2, b3, b4, b5, b6, b7);
    }
    for (; j < r1; ++j) {
        int s = elist[j];
        uint4 v = ((const uint4*)(feat + (size_t)s * DIM))[lane];
        GACC(v, a0, a1, a2, a3, a4, a5, a6, a7);
    }
    a0 += b0; a1 += b1; a2 += b2; a3 += b3;
    a4 += b4; a5 += b5; a6 += b6; a7 += b7;
    float sc = (r1 > r0) ? (1.f / (float)(r1 - r0)) : 0.f;
    uint4 o;
    o.x = (u32)f2bf(a0 * sc) | ((u32)f2bf(a1 * sc) << 16);
    o.y = (u32)f2bf(a2 * sc) | ((u32)f2bf(a3 * sc) << 16);
    o.z = (u32)f2bf(a4 * sc) | ((u32)f2bf(a5 * sc) << 16);
    o.w = (u32)f2bf(a6 * sc) | ((u32)f2bf(a7 * sc) << 16);
    ((uint4*)(meanA + (size_t)node * DIM))[lane] = o;
}

// ---------------- fused transform+update per stage (51 KB LDS) --------------
__global__ __launch_bounds__(256) void stage_fused(
    const u16* __restrict__ meanA, const int* __restrict__ rowptr,
    const u16* __restrict__ Wt, const float* __restrict__ bt,
    const u16* __restrict__ A1, const u16* __restrict__ Wu,
    const float* __restrict__ bu,
    u16* __restrict__ outC, float* __restrict__ outF, int N)
{
    __shared__ u16 Wl[128][136];
    __shared__ u16 Al[64][136];
    const int tid = threadIdx.x;
    const int nb = blockIdx.x * 64;
    const int wave = tid >> 6;
    const int lane = tid & 63;
    const int m = lane & 15;
    const int quad = lane >> 4;
    const int arow = wave * 16 + m;

    #pragma unroll
    for (int i = 0; i < 8; ++i) {
        int c = i * 256 + tid;
        int row = c >> 4;
        int c8 = (c & 15) * 8;
        *(uint4*)&Wl[row][c8] = *(const uint4*)(Wt + row * 128 + c8);
    }
    #pragma unroll
    for (int i = 0; i < 4; ++i) {
        int c = i * 256 + tid;
        int row = c >> 4;
        int c8 = (c & 15) * 8;
        int n = nb + row;
        uint4 v = {0u, 0u, 0u, 0u};
        if (n < N) v = *(const uint4*)(meanA + (size_t)n * DIM + c8);
        *(uint4*)&Al[row][c8] = v;
    }
    __syncthreads();

    v4f acct[8];
    #pragma unroll
    for (int t = 0; t < 8; ++t) acct[t] = (v4f){0.f, 0.f, 0.f, 0.f};
    #pragma unroll
    for (int k0 = 0; k0 < 128; k0 += 32) {
        v8s a = *(const v8s*)&Al[arow][k0 + quad * 8];
        #pragma unroll
        for (int t = 0; t < 8; ++t) {
            v8s b = *(const v8s*)&Wl[t * 16 + m][k0 + quad * 8];
            acct[t] = __builtin_amdgcn_mfma_f32_16x16x32_bf16(a, b, acct[t], 0, 0, 0);
        }
    }
    __syncthreads();

    {
        float btv[8];
        #pragma unroll
        for (int t = 0; t < 8; ++t) btv[t] = bt[t * 16 + m];
        #pragma unroll
        for (int r = 0; r < 4; ++r) {
            int n = nb + wave * 16 + quad * 4 + r;
            bool has = (n < N) && (rowptr[n + 1] > rowptr[n]);
            #pragma unroll
            for (int t = 0; t < 8; ++t) {
                float val = has ? (acct[t][r] + btv[t]) : 0.f;
                Al[wave * 16 + quad * 4 + r][t * 16 + m] = f2bf(val);
            }
        }
    }
    #pragma unroll
    for (int i = 0; i < 8; ++i) {
        int c = i * 256 + tid;
        int row = c >> 4;
        int c8 = (c & 15) * 8;
        *(uint4*)&Wl[row][c8] = *(const uint4*)(Wu + row * 256 + 128 + c8);
    }
    __syncthreads();

    v4f accu[8];
    #pragma unroll
    for (int t = 0; t < 8; ++t) accu[t] = (v4f){0.f, 0.f, 0.f, 0.f};
    #pragma unroll
    for (int k0 = 0; k0 < 128; k0 += 32) {
        v8s a = *(const v8s*)&Al[arow][k0 + quad * 8];
        #pragma unroll
        for (int t = 0; t < 8; ++t) {
            v8s b = *(const v8s*)&Wl[t * 16 + m][k0 + quad * 8];
            accu[t] = __builtin_amdgcn_mfma_f32_16x16x32_bf16(a, b, accu[t], 0, 0, 0);
        }
    }
    __syncthreads();

    #pragma unroll
    for (int i = 0; i < 8; ++i) {
        int c = i * 256 + tid;
        int row = c >> 4;
        int c8 = (c & 15) * 8;
        *(uint4*)&Wl[row][c8] = *(const uint4*)(Wu + row * 256 + c8);
    }
    #pragma unroll
    for (int i = 0; i < 4; ++i) {
        int c = i * 256 + tid;
        int row = c >> 4;
        int c8 = (c & 15) * 8;
        int n = nb + row;
        uint4 v = {0u, 0u, 0u, 0u};
        if (n < N) v = *(const uint4*)(A1 + (size_t)n * DIM + c8);
        *(uint4*)&Al[row][c8] = v;
    }
    __syncthreads();

    #pragma unroll
    for (int k0 = 0; k0 < 128; k0 += 32) {
        v8s a = *(const v8s*)&Al[arow][k0 + quad * 8];
        #pragma unroll
        for (int t = 0; t < 8; ++t) {
            v8s b = *(const v8s*)&Wl[t * 16 + m][k0 + quad * 8];
            accu[t] = __builtin_amdgcn_mfma_f32_16x16x32_bf16(a, b, accu[t], 0, 0, 0);
        }
    }

    float buv[8];
    #pragma unroll
    for (int t = 0; t < 8; ++t) buv[t] = bu[t * 16 + m];
    #pragma unroll
    for (int r = 0; r < 4; ++r) {
        int n = nb + wave * 16 + quad * 4 + r;
        if (n >= N) continue;
        #pragma unroll
        for (int t = 0; t < 8; ++t) {
            float val = accu[t][r] + buv[t];
            val = val > 0.f ? val : 0.f;
            if (outC) outC[(size_t)n * DIM + t * 16 + m] = f2bf(val);
            if (outF) outF[(size_t)n * DIM + t * 16 + m] = val;
        }
    }
}

extern "C" void kernel_launch(void* const* d_in, const int* in_sizes, int n_in,
                              void* d_out, int out_size, void* d_ws, size_t ws_size,
                              hipStream_t stream)
{
    const float* tile_h   = (const float*)d_in[0];
    const float* piece_h  = (const float*)d_in[1];
    const int* tile_src   = (const int*)d_in[2];
    const int* piece_dst  = (const int*)d_in[3];
    const int* piece_src  = (const int*)d_in[4];
    const int* tile_dst   = (const int*)d_in[5];
    const int* t_src      = (const int*)d_in[6];
    const int* t_dst      = (const int*)d_in[7];
    const float* b_t2p = (const float*)d_in[9];
    const float* b_pu  = (const float*)d_in[11];
    const float* b_p2t = (const float*)d_in[13];
    const float* b_tup = (const float*)d_in[15];
    const float* b_t2t = (const float*)d_in[17];
    const float* b_tut = (const float*)d_in[19];

    const int NT  = in_sizes[0] / DIM;   // 50000
    const int NP  = in_sizes[1] / DIM;   // 25000
    const int EPT = in_sizes[2];         // 400000
    const int ETT = in_sizes[6];         // 600000
    const int ET  = 2 * EPT + ETT;       // 1.4M

    const int NBLK = (ET + EPB - 1) / EPB;      // radix chunks (~342, <= CBLK)
    const int n2 = BINS * NBLK;                 // count-matrix size (~175K)
    const int SB = (n2 + 2047) / 2048;          // scan blocks (~86, <=128)

    // ---- workspace layout ----
    char* ws = (char*)d_ws;
    size_t off = 0;
    int* counts = (int*)(ws + off);   off += (size_t)n2 * sizeof(int);
    off = (off + 255) & ~(size_t)255;
    int* countsS = (int*)(ws + off);  off += (size_t)n2 * sizeof(int);
    off = (off + 255) & ~(size_t)255;
    int* gbsum = (int*)(ws + off);    off += (size_t)((SB + 63) & ~63) * sizeof(int);
    off = (off + 255) & ~(size_t)255;
    int* rowptr = (int*)(ws + off);   off += (size_t)(NP + 2 * NT + 3) * sizeof(int);
    off = (off + 255) & ~(size_t)255;
    int* el = (int*)(ws + off);       off += (size_t)ET * sizeof(int);   // unified el1|el2|el3
    off = (off + 255) & ~(size_t)255;
    u16* A = (u16*)(ws + off);        off += (size_t)NT * DIM * sizeof(u16);   // meanA
    off = (off + 255) & ~(size_t)255;
    u16* C = (u16*)(ws + off);        off += (size_t)NT * DIM * sizeof(u16);   // node-mid
    off = (off + 255) & ~(size_t)255;
    u16* arena = (u16*)(ws + off);    // bf16: Th | Ph | 6 weights

    // T (bucketed edges) aliases A: dead once csr_coop completes; A is first
    // written by gather_mean afterwards. ET*4 = 5.6 MB <= 12.8 MB.
    int* T = (int*)A;

    const u32 nTh = (u32)NT * DIM, nPh = (u32)NP * DIM;
    u32 pfx[9];
    pfx[0] = 0;
    pfx[1] = nTh;                  // Ph
    pfx[2] = pfx[1] + nPh;         // W_t2p
    pfx[3] = pfx[2] + 16384;       // W_pu
    pfx[4] = pfx[3] + 32768;       // W_p2t
    pfx[5] = pfx[4] + 16384;       // W_tup
    pfx[6] = pfx[5] + 32768;       // W_t2t
    pfx[7] = pfx[6] + 16384;       // W_tut
    pfx[8] = pfx[7] + 32768;       // total

    u16* Th = arena + pfx[0];
    u16* Ph = arena + pfx[1];
    const u16* Wt2p = arena + pfx[2];
    const u16* Wpu  = arena + pfx[3];
    const u16* Wp2t = arena + pfx[4];
    const u16* Wtup = arena + pfx[5];
    const u16* Wt2t = arena + pfx[6];
    const u16* Wtut = arena + pfx[7];

    int* rp1 = rowptr;
    int* rp2 = rowptr + NP + 1;
    int* rp3 = rowptr + NP + 1 + NT + 1;
    int* el1 = el;
    int* el2 = el + EPT;
    int* el3 = el + 2 * EPT;

    float* out_tile  = (float*)d_out;
    float* out_piece = out_tile + (size_t)NT * DIM;

    dim3 blk(256);
    int n8 = (int)(pfx[8] / 8);
    dim3 g_gp((unsigned)((NP + 15) / 16));
    dim3 g_gt((unsigned)((NT + 15) / 16));
    dim3 g_np((unsigned)((NP + 63) / 64));
    dim3 g_nt((unsigned)((NT + 63) / 64));

    // ---- cooperative CSR build (1 launch replaces 4) ----
    CvtArgs ca;
    ca.s[0] = tile_h; ca.s[1] = piece_h;
    ca.s[2] = (const float*)d_in[8];  ca.s[3] = (const float*)d_in[10];
    ca.s[4] = (const float*)d_in[12]; ca.s[5] = (const float*)d_in[14];
    ca.s[6] = (const float*)d_in[16]; ca.s[7] = (const float*)d_in[18];
    for (int i = 0; i < 9; ++i) ca.pfx[i] = pfx[i];

    int n8v = n8, eptv = EPT, ettv = ETT, npv = NP, ntv = NT;
    int nblkv = NBLK, n2v = n2, sbv = SB;
    u16* arenav = arena;
    const int* tsv = tile_src; const int* pdv = piece_dst;
    const int* psv = piece_src; const int* tdv = tile_dst;
    const int* ttsv = t_src; const int* ttdv = t_dst;
    int* countsv = counts; int* countsSv = countsS; int* gbsumv = gbsum;
    int* Tv = T; int* elv = el; int* rowptrv = rowptr;
    void* cargs[] = {
        &ca, &arenav, &n8v,
        &tsv, &pdv, &psv, &tdv, &ttsv, &ttdv,
        &eptv, &ettv, &npv, &ntv,
        &countsv, &countsSv, &gbsumv, &nblkv, &n2v, &sbv,
        &Tv, &elv, &rowptrv
    };
    hipLaunchCooperativeKernel((void*)csr_coop, dim3(CBLK), dim3(CTHR),
                               cargs, 0, stream);

    // ---- Stage 1: tile -> piece ----
    hipLaunchKernelGGL(gather_mean_kernel, g_gp, blk, 0, stream,
                       Th, el1, rp1, NP, A);
    hipLaunchKernelGGL(stage_fused, g_np, blk, 0, stream,
                       A, rp1, Wt2p, b_t2p, Ph, Wpu, b_pu, C, out_piece, NP);

    // ---- Stage 2: piece -> tile (gather reads C = piece-mid) ----
    hipLaunchKernelGGL(gather_mean_kernel, g_gt, blk, 0, stream,
                       C, el2, rp2, NT, A);
    hipLaunchKernelGGL(stage_fused, g_nt, blk, 0, stream,
                       A, rp2, Wp2t, b_p2t, Th, Wtup, b_tup, C, (float*)nullptr, NT);

    // ---- Stage 3: tile -> tile (gather reads C = tile-mid) ----
    hipLaunchKernelGGL(gather_mean_kernel, g_gt, blk, 0, stream,
                       C, el3, rp3, NT, A);
    hipLaunchKernelGGL(stage_fused, g_nt, blk, 0, stream,
                       A, rp3, Wt2t, b_t2t, C, Wtut, b_tut, (u16*)nullptr, out_tile, NT);
}

// Round 13
// 287.259 us; speedup vs baseline: 1.8309x; 1.8309x over previous
//
#include <hip/hip_runtime.h>
#include <hip/hip_bf16.h>

#define DIM 128
#define EPB 4096      // edges per block in radix phases (342 blocks: occupancy > locality)
#define BINS 512

typedef unsigned short u16;
typedef unsigned int u32;
typedef __attribute__((ext_vector_type(8))) short v8s;
typedef __attribute__((ext_vector_type(4))) float v4f;

__device__ __forceinline__ float bf2f(u16 u) {
    union { unsigned int i; float f; } v;
    v.i = ((unsigned int)u) << 16;
    return v.f;
}

__device__ __forceinline__ u16 f2bf(float f) {
    union { float f; unsigned int i; } v;
    v.f = f;
    unsigned int x = v.i;
    return (u16)((x + 0x7fffu + ((x >> 16) & 1u)) >> 16);
}

__device__ __forceinline__ uint4 pack8(float4 x0, float4 x1) {
    uint4 o;
    o.x = (u32)f2bf(x0.x) | ((u32)f2bf(x0.y) << 16);
    o.y = (u32)f2bf(x0.z) | ((u32)f2bf(x0.w) << 16);
    o.z = (u32)f2bf(x1.x) | ((u32)f2bf(x1.y) << 16);
    o.w = (u32)f2bf(x1.z) | ((u32)f2bf(x1.w) << 16);
    return o;
}

// ---------------- fat kernel: f32->bf16 conversion  ||  bucket histogram ----
struct CvtArgs { const float* s[8]; u32 pfx[9]; };
__global__ __launch_bounds__(256) void cvt_and_count(
    CvtArgs a, u16* __restrict__ dst, int n8, int cvtB,
    const int* __restrict__ piece_dst, const int* __restrict__ tile_dst,
    const int* __restrict__ t_dst, int EPT, int ETT,
    int* __restrict__ counts, int NBLK)
{
    __shared__ int h[BINS];
    const int t = threadIdx.x;
    if (blockIdx.x < cvtB) {
        int g = blockIdx.x * 256 + t;
        if (g >= n8) return;
        u32 flat = (u32)g * 8;
        int seg = 0;
        #pragma unroll
        for (int i = 1; i < 8; ++i) if (flat >= a.pfx[i]) seg = i;
        const float4* fp = (const float4*)(a.s[seg] + (flat - a.pfx[seg]));
        *(uint4*)(dst + flat) = pack8(fp[0], fp[1]);
        return;
    }
    const int blk = blockIdx.x - cvtB;
    for (int d = t; d < BINS; d += 256) h[d] = 0;
    __syncthreads();
    const int ET = 2 * EPT + ETT;
    #pragma unroll 4
    for (int j = 0; j < EPB / 256; ++j) {
        int e = blk * EPB + j * 256 + t;
        if (e < ET) {
            int d;
            if (e < EPT)            d = (piece_dst[e] >> 9);
            else if (e < 2 * EPT)   d = 128 | (tile_dst[e - EPT] >> 9);
            else                    d = 256 | (t_dst[e - 2 * EPT] >> 9);
            atomicAdd(&h[d], 1);
        }
    }
    __syncthreads();
    for (int d = t; d < BINS; d += 256) counts[d * NBLK + blk] = h[d];
}

// ---------------- partial exclusive scan (per-2048 block) -------------------
__global__ __launch_bounds__(256) void scan_gpart(const int* __restrict__ in,
                                                  int* __restrict__ out,
                                                  int* __restrict__ bsum, int n)
{
    __shared__ int ls[256];
    const int blk = blockIdx.x, t = threadIdx.x;
    const int base = blk * 2048;
    int v[8]; int s = 0;
    #pragma unroll
    for (int i = 0; i < 8; ++i) {
        int idx = base + t * 8 + i;
        v[i] = (idx < n) ? in[idx] : 0;
        s += v[i];
    }
    ls[t] = s;
    __syncthreads();
    #pragma unroll
    for (int o = 1; o < 256; o <<= 1) {
        int x = (t >= o) ? ls[t - o] : 0;
        __syncthreads();
        ls[t] += x;
        __syncthreads();
    }
    int run = (t == 0) ? 0 : ls[t - 1];
    #pragma unroll
    for (int i = 0; i < 8; ++i) {
        int idx = base + t * 8 + i;
        if (idx < n) out[idx] = run;
        run += v[i];
    }
    if (t == 255) bsum[blk] = ls[255];
}

// ---------------- radix phase A: scatter into buckets (512 thr/block) -------
__global__ __launch_bounds__(512) void rs_scatter(
    const int* __restrict__ tile_src, const int* __restrict__ piece_dst,
    const int* __restrict__ piece_src, const int* __restrict__ tile_dst,
    const int* __restrict__ t_src, const int* __restrict__ t_dst,
    int EPT, int ETT,
    const int* __restrict__ countsS, const int* __restrict__ bsum, int SB,
    int NBLK, int* __restrict__ T)
{
    __shared__ int p[BINS];
    __shared__ int offp[128];
    const int t = threadIdx.x;
    const int blk = blockIdx.x;
    if (t < SB) offp[t] = bsum[t];
    __syncthreads();
    if (t == 0) {
        int run = 0;
        for (int i = 0; i < SB; ++i) { int v = offp[i]; offp[i] = run; run += v; }
    }
    __syncthreads();
    if (t < BINS) {
        int idx = t * NBLK + blk;
        p[t] = countsS[idx] + offp[idx >> 11];
    }
    __syncthreads();
    const int ET = 2 * EPT + ETT;
    #pragma unroll 4
    for (int j = 0; j < EPB / 512; ++j) {
        int e = blk * EPB + j * 512 + t;
        if (e < ET) {
            int dst, src, d;
            if (e < EPT) {
                dst = piece_dst[e]; src = tile_src[e]; d = dst >> 9;
            } else if (e < 2 * EPT) {
                int le = e - EPT;
                dst = tile_dst[le]; src = piece_src[le]; d = 128 | (dst >> 9);
            } else {
                int le = e - 2 * EPT;
                dst = t_dst[le]; src = t_src[le]; d = 256 | (dst >> 9);
            }
            int pos = atomicAdd(&p[d], 1);
            T[pos] = ((dst & 511) << 17) | src;
        }
    }
}

// ---------------- phase B: per-bucket counting sort + rowptr (512 thr) ------
__global__ __launch_bounds__(512) void bucket_sort(
    const int* __restrict__ T, const int* __restrict__ countsS,
    const int* __restrict__ bsum, int SB, int NBLK, int ET,
    int EPT, int ETT, int NP, int NT,
    int* __restrict__ el, int* __restrict__ rowptr)
{
    const int d = blockIdx.x;
    const int seg = d >> 7;
    if (seg > 2) return;
    const int dhi = d & 127;
    int Nseg, segOff, rb, Eseg;
    if (seg == 0)      { Nseg = NP; segOff = 0;       rb = 0;                 Eseg = EPT; }
    else if (seg == 1) { Nseg = NT; segOff = EPT;     rb = NP + 1;            Eseg = EPT; }
    else               { Nseg = NT; segOff = 2 * EPT; rb = NP + 1 + NT + 1;   Eseg = ETT; }

    __shared__ int hist[BINS];
    __shared__ int pos[BINS];
    __shared__ int ls[BINS];
    __shared__ int offp[128];
    const int t = threadIdx.x;
    if (t < SB) offp[t] = bsum[t];
    __syncthreads();
    if (t == 0) {
        int run = 0;
        for (int i = 0; i < SB; ++i) { int v = offp[i]; offp[i] = run; run += v; }
    }
    __syncthreads();
    int i0 = d * NBLK;
    const int bstart = countsS[i0] + offp[i0 >> 11];
    int bend;
    if (d < BINS - 1) { int i1 = (d + 1) * NBLK; bend = countsS[i1] + offp[i1 >> 11]; }
    else bend = ET;

    if (t < BINS) hist[t] = 0;
    __syncthreads();
    for (int j = bstart + t; j < bend; j += 512)
        atomicAdd(&hist[T[j] >> 17], 1);
    __syncthreads();
    int c0 = (t < BINS) ? hist[t] : 0;
    ls[t & (BINS - 1)] = 0;
    ls[t] = c0;
    __syncthreads();
    #pragma unroll
    for (int o = 1; o < BINS; o <<= 1) {
        int x = (t >= o) ? ls[t - o] : 0;
        __syncthreads();
        ls[t] += x;
        __syncthreads();
    }
    int ex = (t == 0) ? 0 : ls[t - 1];
    pos[t] = bstart + ex;
    __syncthreads();
    {
        int n = dhi * 512 + t;
        if (n < Nseg) rowptr[rb + n] = pos[t] - segOff;
    }
    if (t == 0 && dhi == ((Nseg - 1) >> 9)) rowptr[rb + Nseg] = Eseg;
    __syncthreads();
    for (int j = bstart + t; j < bend; j += 512) {
        int v = T[j];
        int p = atomicAdd(&pos[v >> 17], 1);
        el[p] = v & 0x1ffff;
    }
}

// ---------------- gather-side mean: 16 lanes/row, dwordx4, 8-wide ILP -------
#define GACC(vv, p0, p1, p2, p3, p4, p5, p6, p7) do { \
    p0 += bf2f((u16)((vv).x & 0xffffu)); p1 += bf2f((u16)((vv).x >> 16)); \
    p2 += bf2f((u16)((vv).y & 0xffffu)); p3 += bf2f((u16)((vv).y >> 16)); \
    p4 += bf2f((u16)((vv).z & 0xffffu)); p5 += bf2f((u16)((vv).z >> 16)); \
    p6 += bf2f((u16)((vv).w & 0xffffu)); p7 += bf2f((u16)((vv).w >> 16)); } while (0)

__global__ __launch_bounds__(256) void gather_mean_kernel(
    const u16* __restrict__ feat,
    const int* __restrict__ elist, const int* __restrict__ rowptr,
    int N, u16* __restrict__ meanA)
{
    int node = blockIdx.x * 16 + (threadIdx.x >> 4);
    int lane = threadIdx.x & 15;
    if (node >= N) return;
    int r0 = rowptr[node], r1 = rowptr[node + 1];
    float a0 = 0.f, a1 = 0.f, a2 = 0.f, a3 = 0.f;
    float a4 = 0.f, a5 = 0.f, a6 = 0.f, a7 = 0.f;
    float b0 = 0.f, b1 = 0.f, b2 = 0.f, b3 = 0.f;
    float b4 = 0.f, b5 = 0.f, b6 = 0.f, b7 = 0.f;
    int j = r0;
    for (; j + 8 <= r1; j += 8) {
        int s0 = elist[j],     s1 = elist[j + 1], s2 = elist[j + 2], s3 = elist[j + 3];
        int s4 = elist[j + 4], s5 = elist[j + 5], s6 = elist[j + 6], s7 = elist[j + 7];
        uint4 v0 = ((const uint4*)(feat + (size_t)s0 * DIM))[lane];
        uint4 v1 = ((const uint4*)(feat + (size_t)s1 * DIM))[lane];
        uint4 v2 = ((const uint4*)(feat + (size_t)s2 * DIM))[lane];
        uint4 v3 = ((const uint4*)(feat + (size_t)s3 * DIM))[lane];
        uint4 v4 = ((const uint4*)(feat + (size_t)s4 * DIM))[lane];
        uint4 v5 = ((const uint4*)(feat + (size_t)s5 * DIM))[lane];
        uint4 v6 = ((const uint4*)(feat + (size_t)s6 * DIM))[lane];
        uint4 v7 = ((const uint4*)(feat + (size_t)s7 * DIM))[lane];
        GACC(v0, a0, a1, a2, a3, a4, a5, a6, a7);
        GACC(v1, b0, b1, b2, b3, b4, b5, b6, b7);
        GACC(v2, a0, a1, a2, a3, a4, a5, a6, a7);
        GACC(v3, b0, b1, b2, b3, b4, b5, b6, b7);
        GACC(v4, a0, a1, a2, a3, a4, a5, a6, a7);
        GACC(v5, b0, b1, b2, b3, b4, b5, b6, b7);
        GACC(v6, a0, a1, a2, a3, a4, a5, a6, a7);
        GACC(v7, b0, b1, b2, b3, b4, b5, b6, b7);
    }
    for (; j + 4 <= r1; j += 4) {
        int s0 = elist[j], s1 = elist[j + 1], s2 = elist[j + 2], s3 = elist[j + 3];
        uint4 v0 = ((const uint4*)(feat + (size_t)s0 * DIM))[lane];
        uint4 v1 = ((const uint4*)(feat + (size_t)s1 * DIM))[lane];
        uint4 v2 = ((const uint4*)(feat + (size_t)s2 * DIM))[lane];
        uint4 v3 = ((const uint4*)(feat + (size_t)s3 * DIM))[lane];
        GACC(v0, a0, a1, a2, a3, a4, a5, a6, a7);
        GACC(v1, b0, b1, b2, b3, b4, b5, b6, b7);
        GACC(v2, a0, a1, a2, a3, a4, a5, a6, a7);
        GACC(v3, b0, b1, b2, b3, b4, b5, b6, b7);
    }
    for (; j < r1; ++j) {
        int s = elist[j];
        uint4 v = ((const uint4*)(feat + (size_t)s * DIM))[lane];
        GACC(v, a0, a1, a2, a3, a4, a5, a6, a7);
    }
    a0 += b0; a1 += b1; a2 += b2; a3 += b3;
    a4 += b4; a5 += b5; a6 += b6; a7 += b7;
    float sc = (r1 > r0) ? (1.f / (float)(r1 - r0)) : 0.f;
    uint4 o;
    o.x = (u32)f2bf(a0 * sc) | ((u32)f2bf(a1 * sc) << 16);
    o.y = (u32)f2bf(a2 * sc) | ((u32)f2bf(a3 * sc) << 16);
    o.z = (u32)f2bf(a4 * sc) | ((u32)f2bf(a5 * sc) << 16);
    o.w = (u32)f2bf(a6 * sc) | ((u32)f2bf(a7 * sc) << 16);
    ((uint4*)(meanA + (size_t)node * DIM))[lane] = o;
}

// ---------------- fused transform+update per stage --------------------------
// B = (deg>0) ? meanA @ Wt^T + bt : 0   (kept in LDS)
// out = relu([A1, B] @ Wu^T + bu)
__global__ __launch_bounds__(256) void stage_fused(
    const u16* __restrict__ meanA, const int* __restrict__ rowptr,
    const u16* __restrict__ Wt, const float* __restrict__ bt,
    const u16* __restrict__ A1, const u16* __restrict__ Wu,
    const float* __restrict__ bu,
    u16* __restrict__ outC, float* __restrict__ outF, int N)
{
    __shared__ u16 Wl[128][136];
    __shared__ u16 Al[64][136];
    __shared__ u16 Bl[64][136];
    const int tid = threadIdx.x;
    const int nb = blockIdx.x * 64;
    const int wave = tid >> 6;
    const int lane = tid & 63;
    const int m = lane & 15;
    const int quad = lane >> 4;
    const int arow = wave * 16 + m;

    // ---- stage Wt + meanA ----
    #pragma unroll
    for (int i = 0; i < 8; ++i) {
        int c = i * 256 + tid;
        int row = c >> 4;
        int c8 = (c & 15) * 8;
        *(uint4*)&Wl[row][c8] = *(const uint4*)(Wt + row * 128 + c8);
    }
    #pragma unroll
    for (int i = 0; i < 4; ++i) {
        int c = i * 256 + tid;
        int row = c >> 4;
        int c8 = (c & 15) * 8;
        int n = nb + row;
        uint4 v = {0u, 0u, 0u, 0u};
        if (n < N) v = *(const uint4*)(meanA + (size_t)n * DIM + c8);
        *(uint4*)&Al[row][c8] = v;
    }
    __syncthreads();

    // ---- transform MFMA ----
    v4f acct[8];
    #pragma unroll
    for (int t = 0; t < 8; ++t) acct[t] = (v4f){0.f, 0.f, 0.f, 0.f};
    #pragma unroll
    for (int k0 = 0; k0 < 128; k0 += 32) {
        v8s a = *(const v8s*)&Al[arow][k0 + quad * 8];
        #pragma unroll
        for (int t = 0; t < 8; ++t) {
            v8s b = *(const v8s*)&Wl[t * 16 + m][k0 + quad * 8];
            acct[t] = __builtin_amdgcn_mfma_f32_16x16x32_bf16(a, b, acct[t], 0, 0, 0);
        }
    }
    __syncthreads();   // all waves done reading Wl/Al

    // ---- B -> Bl (bias + deg-mask, bf16) ----
    {
        float btv[8];
        #pragma unroll
        for (int t = 0; t < 8; ++t) btv[t] = bt[t * 16 + m];
        #pragma unroll
        for (int r = 0; r < 4; ++r) {
            int n = nb + wave * 16 + quad * 4 + r;
            bool has = (n < N) && (rowptr[n + 1] > rowptr[n]);
            #pragma unroll
            for (int t = 0; t < 8; ++t) {
                float val = has ? (acct[t][r] + btv[t]) : 0.f;
                Bl[wave * 16 + quad * 4 + r][t * 16 + m] = f2bf(val);
            }
        }
    }
    // ---- restage Wl <- Wu half0, Al <- A1 ----
    #pragma unroll
    for (int i = 0; i < 8; ++i) {
        int c = i * 256 + tid;
        int row = c >> 4;
        int c8 = (c & 15) * 8;
        *(uint4*)&Wl[row][c8] = *(const uint4*)(Wu + row * 256 + c8);
    }
    #pragma unroll
    for (int i = 0; i < 4; ++i) {
        int c = i * 256 + tid;
        int row = c >> 4;
        int c8 = (c & 15) * 8;
        int n = nb + row;
        uint4 v = {0u, 0u, 0u, 0u};
        if (n < N) v = *(const uint4*)(A1 + (size_t)n * DIM + c8);
        *(uint4*)&Al[row][c8] = v;
    }
    __syncthreads();

    // ---- update MFMA half0 (A1 part) ----
    v4f accu[8];
    #pragma unroll
    for (int t = 0; t < 8; ++t) accu[t] = (v4f){0.f, 0.f, 0.f, 0.f};
    #pragma unroll
    for (int k0 = 0; k0 < 128; k0 += 32) {
        v8s a = *(const v8s*)&Al[arow][k0 + quad * 8];
        #pragma unroll
        for (int t = 0; t < 8; ++t) {
            v8s b = *(const v8s*)&Wl[t * 16 + m][k0 + quad * 8];
            accu[t] = __builtin_amdgcn_mfma_f32_16x16x32_bf16(a, b, accu[t], 0, 0, 0);
        }
    }
    __syncthreads();

    // ---- restage Wl <- Wu half1 ----
    #pragma unroll
    for (int i = 0; i < 8; ++i) {
        int c = i * 256 + tid;
        int row = c >> 4;
        int c8 = (c & 15) * 8;
        *(uint4*)&Wl[row][c8] = *(const uint4*)(Wu + row * 256 + 128 + c8);
    }
    __syncthreads();

    // ---- update MFMA half1 (B part, from Bl) ----
    #pragma unroll
    for (int k0 = 0; k0 < 128; k0 += 32) {
        v8s a = *(const v8s*)&Bl[arow][k0 + quad * 8];
        #pragma unroll
        for (int t = 0; t < 8; ++t) {
            v8s b = *(const v8s*)&Wl[t * 16 + m][k0 + quad * 8];
            accu[t] = __builtin_amdgcn_mfma_f32_16x16x32_bf16(a, b, accu[t], 0, 0, 0);
        }
    }

    // ---- epilogue ----
    float buv[8];
    #pragma unroll
    for (int t = 0; t < 8; ++t) buv[t] = bu[t * 16 + m];
    #pragma unroll
    for (int r = 0; r < 4; ++r) {
        int n = nb + wave * 16 + quad * 4 + r;
        if (n >= N) continue;
        #pragma unroll
        for (int t = 0; t < 8; ++t) {
            float val = accu[t][r] + buv[t];
            val = val > 0.f ? val : 0.f;
            if (outC) outC[(size_t)n * DIM + t * 16 + m] = f2bf(val);
            if (outF) outF[(size_t)n * DIM + t * 16 + m] = val;
        }
    }
}

extern "C" void kernel_launch(void* const* d_in, const int* in_sizes, int n_in,
                              void* d_out, int out_size, void* d_ws, size_t ws_size,
                              hipStream_t stream)
{
    const float* tile_h   = (const float*)d_in[0];
    const float* piece_h  = (const float*)d_in[1];
    const int* tile_src   = (const int*)d_in[2];
    const int* piece_dst  = (const int*)d_in[3];
    const int* piece_src  = (const int*)d_in[4];
    const int* tile_dst   = (const int*)d_in[5];
    const int* t_src      = (const int*)d_in[6];
    const int* t_dst      = (const int*)d_in[7];
    const float* b_t2p = (const float*)d_in[9];
    const float* b_pu  = (const float*)d_in[11];
    const float* b_p2t = (const float*)d_in[13];
    const float* b_tup = (const float*)d_in[15];
    const float* b_t2t = (const float*)d_in[17];
    const float* b_tut = (const float*)d_in[19];

    const int NT  = in_sizes[0] / DIM;   // 50000
    const int NP  = in_sizes[1] / DIM;   // 25000
    const int EPT = in_sizes[2];         // 400000
    const int ETT = in_sizes[6];         // 600000
    const int ET  = 2 * EPT + ETT;       // 1.4M

    const int NBLK = (ET + EPB - 1) / EPB;      // radix blocks (~342)
    const int n2 = BINS * NBLK;                 // count-matrix size (~175K)
    const int SB = (n2 + 2047) / 2048;          // scan blocks (~86, must be <=128)

    // ---- workspace layout ----
    char* ws = (char*)d_ws;
    size_t off = 0;
    int* counts = (int*)(ws + off);   off += (size_t)n2 * sizeof(int);
    off = (off + 255) & ~(size_t)255;
    int* countsS = (int*)(ws + off);  off += (size_t)n2 * sizeof(int);
    off = (off + 255) & ~(size_t)255;
    int* gbsum = (int*)(ws + off);    off += (size_t)((SB + 63) & ~63) * sizeof(int);
    off = (off + 255) & ~(size_t)255;
    int* rowptr = (int*)(ws + off);   off += (size_t)(NP + 2 * NT + 3) * sizeof(int);
    off = (off + 255) & ~(size_t)255;
    int* el = (int*)(ws + off);       off += (size_t)ET * sizeof(int);   // unified el1|el2|el3
    off = (off + 255) & ~(size_t)255;
    u16* A = (u16*)(ws + off);        off += (size_t)NT * DIM * sizeof(u16);   // meanA
    off = (off + 255) & ~(size_t)255;
    u16* C = (u16*)(ws + off);        off += (size_t)NT * DIM * sizeof(u16);   // node-mid
    off = (off + 255) & ~(size_t)255;
    u16* arena = (u16*)(ws + off);    // bf16: Th | Ph | 6 weights

    // T (bucketed edges) aliases A: dead once bucket_sort completes, and A is
    // first written by gather_mean afterwards. ET*4 = 5.6 MB <= 12.8 MB.
    int* T = (int*)A;

    const u32 nTh = (u32)NT * DIM, nPh = (u32)NP * DIM;
    u32 pfx[9];
    pfx[0] = 0;
    pfx[1] = nTh;                  // Ph
    pfx[2] = pfx[1] + nPh;         // W_t2p
    pfx[3] = pfx[2] + 16384;       // W_pu
    pfx[4] = pfx[3] + 32768;       // W_p2t
    pfx[5] = pfx[4] + 16384;       // W_tup
    pfx[6] = pfx[5] + 32768;       // W_t2t
    pfx[7] = pfx[6] + 16384;       // W_tut
    pfx[8] = pfx[7] + 32768;       // total

    u16* Th = arena + pfx[0];
    u16* Ph = arena + pfx[1];
    const u16* Wt2p = arena + pfx[2];
    const u16* Wpu  = arena + pfx[3];
    const u16* Wp2t = arena + pfx[4];
    const u16* Wtup = arena + pfx[5];
    const u16* Wt2t = arena + pfx[6];
    const u16* Wtut = arena + pfx[7];

    int* rp1 = rowptr;
    int* rp2 = rowptr + NP + 1;
    int* rp3 = rowptr + NP + 1 + NT + 1;
    int* el1 = el;
    int* el2 = el + EPT;
    int* el3 = el + 2 * EPT;

    float* out_tile  = (float*)d_out;
    float* out_piece = out_tile + (size_t)NT * DIM;

    dim3 blk(256);
    dim3 blk2(512);
    int n8 = (int)(pfx[8] / 8);
    const int cvtB = (n8 + 255) / 256;
    dim3 g_fat((unsigned)(cvtB + NBLK));
    dim3 g_rs((unsigned)NBLK);
    dim3 g_scan((unsigned)SB);
    dim3 g_bs((unsigned)BINS);
    dim3 g_gp((unsigned)((NP + 15) / 16));
    dim3 g_gt((unsigned)((NT + 15) / 16));
    dim3 g_np((unsigned)((NP + 63) / 64));
    dim3 g_nt((unsigned)((NT + 63) / 64));

    // ---- conversions || histogram (1 fat launch) ----
    CvtArgs ca;
    ca.s[0] = tile_h; ca.s[1] = piece_h;
    ca.s[2] = (const float*)d_in[8];  ca.s[3] = (const float*)d_in[10];
    ca.s[4] = (const float*)d_in[12]; ca.s[5] = (const float*)d_in[14];
    ca.s[6] = (const float*)d_in[16]; ca.s[7] = (const float*)d_in[18];
    for (int i = 0; i < 9; ++i) ca.pfx[i] = pfx[i];
    hipLaunchKernelGGL(cvt_and_count, g_fat, blk, 0, stream,
                       ca, arena, n8, cvtB,
                       piece_dst, tile_dst, t_dst, EPT, ETT, counts, NBLK);

    // ---- CSR build via 2-phase bucket sort (no device atomics) ----
    hipLaunchKernelGGL(scan_gpart, g_scan, blk, 0, stream, counts, countsS, gbsum, n2);
    hipLaunchKernelGGL(rs_scatter, g_rs, blk2, 0, stream,
                       tile_src, piece_dst, piece_src, tile_dst, t_src, t_dst,
                       EPT, ETT, countsS, gbsum, SB, NBLK, T);
    hipLaunchKernelGGL(bucket_sort, g_bs, blk2, 0, stream,
                       T, countsS, gbsum, SB, NBLK, ET, EPT, ETT, NP, NT, el, rowptr);

    // ---- Stage 1: tile -> piece ----
    hipLaunchKernelGGL(gather_mean_kernel, g_gp, blk, 0, stream,
                       Th, el1, rp1, NP, A);
    hipLaunchKernelGGL(stage_fused, g_np, blk, 0, stream,
                       A, rp1, Wt2p, b_t2p, Ph, Wpu, b_pu, C, out_piece, NP);

    // ---- Stage 2: piece -> tile (gather reads C = piece-mid) ----
    hipLaunchKernelGGL(gather_mean_kernel, g_gt, blk, 0, stream,
                       C, el2, rp2, NT, A);
    hipLaunchKernelGGL(stage_fused, g_nt, blk, 0, stream,
                       A, rp2, Wp2t, b_p2t, Th, Wtup, b_tup, C, (float*)nullptr, NT);

    // ---- Stage 3: tile -> tile (gather reads C = tile-mid) ----
    hipLaunchKernelGGL(gather_mean_kernel, g_gt, blk, 0, stream,
                       C, el3, rp3, NT, A);
    hipLaunchKernelGGL(stage_fused, g_nt, blk, 0, stream,
                       A, rp3, Wt2t, b_t2t, C, Wtut, b_tut, (u16*)nullptr, out_tile, NT);
}